// Round 14
// baseline (240.526 us; speedup 1.0000x reference)
//
#include <hip/hip_runtime.h>
#include <hip/hip_bf16.h>

// b=1, c=256, h=w=64 -> n=4096 pixels, 4 heads, hd=64, 32 groups x 8 ch.
// scale = hd^-0.5 = 0.125, folded into Wq (phase A) and bq (phase B epilogue).
#define NPIX 4096
#define CCH  256
#define HD   64
#define GSIZE 32768   // 8 ch * 4096 pix per group

typedef __bf16 bf16x8 __attribute__((ext_vector_type(8)));
typedef __bf16 bf16x4 __attribute__((ext_vector_type(4)));
typedef float  f32x4  __attribute__((ext_vector_type(4)));

// MFMA 16x16x32_bf16 layouts (verified m89/m91; used R2-R12):
//   A[m=lane&15][k=quad*8+j]; B[k=quad*8+j][n=lane&15]; C: row=quad*4+reg, col=lane&15

// Phase B (gn_qkv) LDS layout
#define XPITCH 264   // X panel pitch (bf16)

// Phase C (attn, exact R9 dataflow) LDS layout
#define KPITCH 72    // kt [key128][d64] pitch, 144 B rows
#define VPITCH 136   // vt [d64][key128] pitch, 272 B rows
#define PPIT   40    // pt per-wave [row64][key32] pitch, 80 B rows
#define KBUF   (128 * KPITCH)           // 9216 elems
#define VBUF   (64 * VPITCH)            // 8704 elems
#define OFF_V  (2 * KBUF * 2)           // 36864 B
#define OFF_P  (OFF_V + 2 * VBUF * 2)   // 71680 B
#define SMEMSZ (OFF_P + 4 * 64 * PPIT * 2)  // 92160 B  (max over all phases)

// ---------------------------------------------------------------------------
// Grid barrier WITHOUT cooperative launch (R13's coop launch failed to run).
// Safe: LDS 92160 B -> 1 block/CU and grid == 256 == CU count, so all blocks
// are co-resident by construction; spin cannot deadlock. Device-scope
// acq/rel atomics + threadfence give cross-XCD visibility (G16).
// ---------------------------------------------------------------------------
__device__ __forceinline__ void grid_barrier(unsigned* cnt, unsigned target)
{
    __syncthreads();
    if (threadIdx.x == 0) {
        __threadfence();   // release: drain + write back this block's stores
        __hip_atomic_fetch_add(cnt, 1u, __ATOMIC_ACQ_REL, __HIP_MEMORY_SCOPE_AGENT);
        while (__hip_atomic_load(cnt, __ATOMIC_ACQUIRE, __HIP_MEMORY_SCOPE_AGENT) < target)
            __builtin_amdgcn_s_sleep(2);
        __threadfence();   // acquire: invalidate stale cache before phase reads
    }
    __syncthreads();
}

// ---------------------------------------------------------------------------
// ONE kernel, plain launch: grid 256 x 256 thr, 92160 B LDS -> 1 block/CU.
//  A: stats partials (256 segs) + weight fp32->bf16 (Wq x0.125)
//  B: gn_qkv, 384 persistent units (64 pixblk x {Q,K,V} x 2 oc-halves)
//  C: attention == R9 verbatim (47 us proven)
//  D: proj+residual, 256 units (128 pixblk32 x 2 oc-halves)
// ---------------------------------------------------------------------------
__global__ __launch_bounds__(256, 1) void fused_all(
    const float* __restrict__ X, const float* __restrict__ gamma,
    const float* __restrict__ beta,
    const float* __restrict__ Wq, const float* __restrict__ bq,
    const float* __restrict__ Wk, const float* __restrict__ bk,
    const float* __restrict__ Wv, const float* __restrict__ bv,
    const float* __restrict__ Wp, const float* __restrict__ bp,
    float* __restrict__ Out,
    float* __restrict__ psum, float* __restrict__ pssq, __bf16* __restrict__ Wb,
    __bf16* __restrict__ Qb, __bf16* __restrict__ Kb, __bf16* __restrict__ Vb,
    __bf16* __restrict__ Sb, unsigned* __restrict__ bar)
{
    __shared__ __align__(16) char smem[SMEMSZ];

    const int t = threadIdx.x, lane = t & 63, wave = t >> 6;
    const int l16 = lane & 15, quad = lane >> 4;
    const int bid = blockIdx.x;

    // ======================= Phase A: stats + wconv ========================
    {
        const float* base = X + bid * 4096;   // (g = bid>>3, seg = bid&7)
        float sum = 0.f, ssq = 0.f;
        #pragma unroll
        for (int k = 0; k < 4; ++k) {
            float4 v = *(const float4*)(base + t * 4 + k * 1024);
            sum += v.x + v.y + v.z + v.w;
            ssq += v.x * v.x + v.y * v.y + v.z * v.z + v.w * v.w;
        }
        #pragma unroll
        for (int off = 1; off < 64; off <<= 1) {
            sum += __shfl_xor(sum, off);
            ssq += __shfl_xor(ssq, off);
        }
        float* red = (float*)smem;   // [2][4]
        if ((t & 63) == 0) { red[wave] = sum; red[4 + wave] = ssq; }
        __syncthreads();
        if (t == 0) {
            psum[bid] = red[0] + red[1] + red[2] + red[3];
            pssq[bid] = red[4] + red[5] + red[6] + red[7];
        }
        // weight convert: 4 elems/thread, 256x256 threads cover 262144
        const int j0 = (bid * 256 + t) * 4;
        const int m  = j0 >> 16;
        const float* W = (m == 0) ? Wq : (m == 1) ? Wk : (m == 2) ? Wv : Wp;
        const float sc = (m == 0) ? 0.125f : 1.f;
        float4 v = *(const float4*)(W + (j0 & 65535));
        bf16x4 o;
        o[0] = (__bf16)(v.x * sc); o[1] = (__bf16)(v.y * sc);
        o[2] = (__bf16)(v.z * sc); o[3] = (__bf16)(v.w * sc);
        *(bf16x4*)(Wb + j0) = o;
    }
    grid_barrier(bar + 0, 256);

    // ======================= Phase B: gn_qkv (384 units) ===================
    {
        __bf16* tile = (__bf16*)smem;                  // 64*XPITCH bf16 = 33792 B
        float*  al   = (float*)(smem + 33792);         // 256 f32
        float*  bl   = al + 256;

        for (int u = bid; u < 384; u += 256) {
            __syncthreads();   // LDS reuse guard (prev unit / phase A)
            const int p0 = (u & 63) * 64;
            const int zy = u >> 6;           // 0..5
            const int z = zy >> 1, och = zy & 1;

            {
                const int g = t >> 3;
                float s = 0.f, q = 0.f;
                #pragma unroll
                for (int j = 0; j < 8; ++j) { s += psum[g * 8 + j]; q += pssq[g * 8 + j]; }
                const float mu  = s * (1.f / GSIZE);
                const float var = q * (1.f / GSIZE) - mu * mu;
                const float a = gamma[t] * rsqrtf(var + 1e-6f);
                al[t] = a;
                bl[t] = beta[t] - mu * a;
            }
            __syncthreads();

            #pragma unroll 4
            for (int i = 0; i < 16; ++i) {
                const int c4 = wave * 64 + i * 4;
                f32x4 a4 = *(const f32x4*)(al + c4);
                f32x4 b4 = *(const f32x4*)(bl + c4);
                bf16x4 pk;
                pk[0] = (__bf16)(X[(c4 + 0) * NPIX + p0 + lane] * a4[0] + b4[0]);
                pk[1] = (__bf16)(X[(c4 + 1) * NPIX + p0 + lane] * a4[1] + b4[1]);
                pk[2] = (__bf16)(X[(c4 + 2) * NPIX + p0 + lane] * a4[2] + b4[2]);
                pk[3] = (__bf16)(X[(c4 + 3) * NPIX + p0 + lane] * a4[3] + b4[3]);
                *(bf16x4*)(tile + lane * XPITCH + c4) = pk;
            }
            __syncthreads();

            const int pw = wave * 16;
            bf16x8 xf[8];
            #pragma unroll
            for (int kc = 0; kc < 8; ++kc)
                xf[kc] = *(const bf16x8*)(tile + (pw + l16) * XPITCH + kc * 32 + quad * 8);

            const __bf16* Wz = Wb + z * 65536;
            const float* bias = (z == 0) ? bq : (z == 1) ? bk : bv;

            if (z < 2) {
                const float qs = (z == 0) ? 0.125f : 1.f;
                __bf16* dst = (z == 0) ? Qb : Kb;
                #pragma unroll
                for (int grp = 0; grp < 2; ++grp) {
                    f32x4 acc[4] = {};
                    #pragma unroll
                    for (int kc = 0; kc < 8; ++kc) {
                        #pragma unroll
                        for (int uu = 0; uu < 4; ++uu) {
                            bf16x8 wf = *(const bf16x8*)(Wz + (och * 128 + (grp * 4 + uu) * 16 + l16) * CCH + kc * 32 + quad * 8);
                            acc[uu] = __builtin_amdgcn_mfma_f32_16x16x32_bf16(wf, xf[kc], acc[uu], 0, 0, 0);
                        }
                    }
                    #pragma unroll
                    for (int uu = 0; uu < 4; ++uu) {
                        const int ot = och * 8 + grp * 4 + uu;    // 0..15
                        f32x4 bz = *(const f32x4*)(bias + och * 128 + (grp * 4 + uu) * 16 + quad * 4);
                        bf16x4 o;
                        o[0] = (__bf16)(acc[uu][0] + bz[0] * qs);
                        o[1] = (__bf16)(acc[uu][1] + bz[1] * qs);
                        o[2] = (__bf16)(acc[uu][2] + bz[2] * qs);
                        o[3] = (__bf16)(acc[uu][3] + bz[3] * qs);
                        const int head = ot >> 2, dloc = (ot & 3) * 16 + quad * 4;
                        *(bf16x4*)(dst + head * (NPIX * HD) + (p0 + pw + l16) * HD + dloc) = o;
                    }
                }
            } else {
                #pragma unroll
                for (int grp = 0; grp < 2; ++grp) {
                    f32x4 acc[4] = {};
                    #pragma unroll
                    for (int kc = 0; kc < 8; ++kc) {
                        #pragma unroll
                        for (int uu = 0; uu < 4; ++uu) {
                            bf16x8 wf = *(const bf16x8*)(Wz + (och * 128 + (grp * 4 + uu) * 16 + l16) * CCH + kc * 32 + quad * 8);
                            acc[uu] = __builtin_amdgcn_mfma_f32_16x16x32_bf16(xf[kc], wf, acc[uu], 0, 0, 0);
                        }
                    }
                    #pragma unroll
                    for (int uu = 0; uu < 4; ++uu) {
                        const int oc = och * 128 + (grp * 4 + uu) * 16 + l16;
                        const float bz = bias[oc];
                        bf16x4 o;
                        o[0] = (__bf16)(acc[uu][0] + bz); o[1] = (__bf16)(acc[uu][1] + bz);
                        o[2] = (__bf16)(acc[uu][2] + bz); o[3] = (__bf16)(acc[uu][3] + bz);
                        *(bf16x4*)(Vb + oc * NPIX + p0 + pw + quad * 4) = o;
                    }
                }
            }
        }
    }
    grid_barrier(bar + 1, 256);

    // ======================= Phase C: attention (R9 verbatim) ==============
    {
        __bf16* ktls = (__bf16*)smem;
        __bf16* vtls = (__bf16*)(smem + OFF_V);
        __bf16* ptls = (__bf16*)(smem + OFF_P);
        float*  co   = (float*)smem;                 // merge overlay (after loop)
        float*  cl   = (float*)(smem + 69632);

        const int head = (bid & 7) >> 1;                   // XCD-pair pinning
        const int qt   = ((bid >> 3) << 1) | (bid & 1);    // 0..63
        const int p0   = qt * 64;

        const __bf16* Qh = Qb + head * (NPIX * HD);
        const __bf16* Kh = Kb + head * (NPIX * HD);
        const __bf16* Vh = Vb + head * (HD * NPIX);

        bf16x8 qf[4][2];
        #pragma unroll
        for (int rt = 0; rt < 4; ++rt) {
            const __bf16* qp = Qh + (p0 + rt * 16 + l16) * HD + quad * 8;
            qf[rt][0] = *(const bf16x8*)(qp);
            qf[rt][1] = *(const bf16x8*)(qp + 32);
        }

        bf16x8 ones;
        #pragma unroll
        for (int j = 0; j < 8; ++j) ones[j] = (__bf16)1.0f;

        f32x4 l_acc[4] = {};
        f32x4 o_acc[4][4] = {};   // [dt][rt]

        __bf16* ptw = ptls + wave * (64 * PPIT);

        bf16x8 kpre[4], vpre[4];
        #pragma unroll
        for (int i = 0; i < 4; ++i) {
            const int c = t + 256 * i;
            kpre[i] = *(const bf16x8*)(Kh + (c >> 3) * HD + (c & 7) * 8);
            vpre[i] = *(const bf16x8*)(Vh + (c >> 4) * NPIX + (c & 15) * 8);
        }

        for (int it = 0; it < 32; ++it) {
            const int b = it & 1;
            __bf16* ktb = ktls + b * KBUF;
            __bf16* vtb = vtls + b * VBUF;

            #pragma unroll
            for (int i = 0; i < 4; ++i) {
                const int c = t + 256 * i;
                *(bf16x8*)(ktb + (c >> 3) * KPITCH + (c & 7) * 8)  = kpre[i];
                *(bf16x8*)(vtb + (c >> 4) * VPITCH + (c & 15) * 8) = vpre[i];
            }
            __syncthreads();

            if (it < 31) {
                const int kb = (it + 1) * 128;
                #pragma unroll
                for (int i = 0; i < 4; ++i) {
                    const int c = t + 256 * i;
                    kpre[i] = *(const bf16x8*)(Kh + (kb + (c >> 3)) * HD + (c & 7) * 8);
                    vpre[i] = *(const bf16x8*)(Vh + (c >> 4) * NPIX + kb + (c & 15) * 8);
                }
            }

            bf16x8 kf[2][2], vf[4];
            #pragma unroll
            for (int kt = 0; kt < 2; ++kt) {
                const __bf16* kp = ktb + (wave * 32 + kt * 16 + l16) * KPITCH + quad * 8;
                kf[kt][0] = *(const bf16x8*)(kp);
                kf[kt][1] = *(const bf16x8*)(kp + 32);
            }
            #pragma unroll
            for (int dt = 0; dt < 4; ++dt)
                vf[dt] = *(const bf16x8*)(vtb + (dt * 16 + l16) * VPITCH + wave * 32 + quad * 8);

            f32x4 st[2][4] = {};
            #pragma unroll
            for (int kt = 0; kt < 2; ++kt)
                #pragma unroll
                for (int rt = 0; rt < 4; ++rt) {
                    st[kt][rt] = __builtin_amdgcn_mfma_f32_16x16x32_bf16(kf[kt][0], qf[rt][0], st[kt][rt], 0, 0, 0);
                    st[kt][rt] = __builtin_amdgcn_mfma_f32_16x16x32_bf16(kf[kt][1], qf[rt][1], st[kt][rt], 0, 0, 0);
                }

            #pragma unroll
            for (int kt = 0; kt < 2; ++kt)
                #pragma unroll
                for (int rt = 0; rt < 4; ++rt) {
                    bf16x4 p;
                    p[0] = (__bf16)__expf(st[kt][rt][0]);
                    p[1] = (__bf16)__expf(st[kt][rt][1]);
                    p[2] = (__bf16)__expf(st[kt][rt][2]);
                    p[3] = (__bf16)__expf(st[kt][rt][3]);
                    *(bf16x4*)(ptw + (rt * 16 + l16) * PPIT + kt * 16 + quad * 4) = p;
                }

            bf16x8 bp2[4];
            #pragma unroll
            for (int rt = 0; rt < 4; ++rt)
                bp2[rt] = *(const bf16x8*)(ptw + (rt * 16 + l16) * PPIT + quad * 8);

            #pragma unroll
            for (int rt = 0; rt < 4; ++rt)
                l_acc[rt] = __builtin_amdgcn_mfma_f32_16x16x32_bf16(ones, bp2[rt], l_acc[rt], 0, 0, 0);

            #pragma unroll
            for (int dt = 0; dt < 4; ++dt)
                #pragma unroll
                for (int rt = 0; rt < 4; ++rt)
                    o_acc[dt][rt] = __builtin_amdgcn_mfma_f32_16x16x32_bf16(vf[dt], bp2[rt], o_acc[dt][rt], 0, 0, 0);
            // no trailing barrier: next iter writes buf b^1 while stragglers read b
        }

        __syncthreads();   // all K/V/P LDS use done before merge overlay

        #pragma unroll
        for (int dt = 0; dt < 4; ++dt)
            #pragma unroll
            for (int rt = 0; rt < 4; ++rt)
                *(f32x4*)(co + wave * 4352 + (rt * 16 + l16) * 68 + dt * 16 + quad * 4) = o_acc[dt][rt];
        if (quad == 0) {
            #pragma unroll
            for (int rt = 0; rt < 4; ++rt)
                cl[wave * 64 + rt * 16 + l16] = l_acc[rt][0];
        }
        __syncthreads();

        {
            const int row = t >> 2, dc = (t & 3) * 16;
            const float l = cl[row] + cl[64 + row] + cl[128 + row] + cl[192 + row];
            const float inv = 1.f / l;
            f32x4 s[4];
            #pragma unroll
            for (int j = 0; j < 4; ++j) {
                s[j] = f32x4{0.f, 0.f, 0.f, 0.f};
                #pragma unroll
                for (int w = 0; w < 4; ++w)
                    s[j] += *(const f32x4*)(co + w * 4352 + row * 68 + dc + j * 4);
            }
            bf16x8 o1, o2;
            #pragma unroll
            for (int j = 0; j < 4; ++j) {
                o1[j]     = (__bf16)(s[0][j] * inv);
                o1[j + 4] = (__bf16)(s[1][j] * inv);
                o2[j]     = (__bf16)(s[2][j] * inv);
                o2[j + 4] = (__bf16)(s[3][j] * inv);
            }
            __bf16* dst = Sb + (p0 + row) * CCH + head * HD + dc;
            *(bf16x8*)(dst)     = o1;
            *(bf16x8*)(dst + 8) = o2;
        }
    }
    grid_barrier(bar + 2, 256);

    // ======================= Phase D: proj + residual ======================
    {
        __bf16* Bs = (__bf16*)smem;     // 32 * XPITCH bf16 = 16896 B

        const int p0  = (bid >> 1) * 32;
        const int och = bid & 1;

        #pragma unroll
        for (int pg = 0; pg < 4; ++pg) {
            bf16x8 v = *(const bf16x8*)(Sb + t * NPIX + p0 + pg * 8);
            #pragma unroll
            for (int j = 0; j < 8; ++j)
                Bs[(pg * 8 + j) * XPITCH + t] = v[j];
        }
        __syncthreads();

        const int pixset = wave & 1, ocset = wave >> 1;
        bf16x8 af[8];
        #pragma unroll
        for (int kc = 0; kc < 8; ++kc)
            af[kc] = *(const bf16x8*)(Bs + (pixset * 16 + l16) * XPITCH + kc * 32 + quad * 8);

        const __bf16* Wpb = Wb + 3 * 65536;
        #pragma unroll
        for (int u = 0; u < 4; ++u) {
            f32x4 acc = {};
            const int oc_t = och * 128 + ocset * 64 + u * 16;
            #pragma unroll
            for (int kc = 0; kc < 8; ++kc) {
                bf16x8 wf = *(const bf16x8*)(Wpb + (oc_t + l16) * CCH + kc * 32 + quad * 8);
                acc = __builtin_amdgcn_mfma_f32_16x16x32_bf16(af[kc], wf, acc, 0, 0, 0);
            }
            const int oc  = oc_t + l16;
            const int pix = p0 + pixset * 16 + quad * 4;
            const float bz = bp[oc];
            f32x4 r4 = *(const f32x4*)(X + oc * NPIX + pix);
            f32x4 y;
            y[0] = acc[0] + bz + r4[0];
            y[1] = acc[1] + bz + r4[1];
            y[2] = acc[2] + bz + r4[2];
            y[3] = acc[3] + bz + r4[3];
            *(f32x4*)(Out + oc * NPIX + pix) = y;
        }
    }
}

// ---------------------------------------------------------------------------
extern "C" void kernel_launch(void* const* d_in, const int* in_sizes, int n_in,
                              void* d_out, int out_size, void* d_ws, size_t ws_size,
                              hipStream_t stream)
{
    const float* x     = (const float*)d_in[0];
    const float* gamma = (const float*)d_in[1];
    const float* beta  = (const float*)d_in[2];
    const float* Wq    = (const float*)d_in[3];
    const float* bq    = (const float*)d_in[4];
    const float* Wk    = (const float*)d_in[5];
    const float* bk    = (const float*)d_in[6];
    const float* Wv    = (const float*)d_in[7];
    const float* bv    = (const float*)d_in[8];
    const float* Wp    = (const float*)d_in[9];
    const float* bp    = (const float*)d_in[10];
    float* out = (float*)d_out;

    char* ws = (char*)d_ws;
    float*    psum = (float*)(ws);                // 1KB stats partial sums
    float*    pssq = (float*)(ws + 1024);         // 1KB
    unsigned* bar  = (unsigned*)(ws + 4096);      // 3 barrier counters
    __bf16*   Wb   = (__bf16*)(ws + 65536);       // 512KB bf16 4x[256][256]
    __bf16*   Qb   = (__bf16*)(ws + (1 << 20));   // 2MB bf16 [head][pix][64]
    __bf16*   Kb   = (__bf16*)(ws + (3 << 20));   // 2MB bf16 [head][pix][64]
    __bf16*   Vb   = (__bf16*)(ws + (5 << 20));   // 2MB bf16 [c][pix]
    __bf16*   Sb   = (__bf16*)(ws + (7 << 20));   // 2MB bf16 flat F

    // zero barrier counters (ws is re-poisoned to 0xAA before every launch)
    hipMemsetAsync(bar, 0, 64, stream);

    fused_all<<<256, 256, 0, stream>>>(x, gamma, beta,
                                       Wq, bq, Wk, bk, Wv, bv, Wp, bp,
                                       out, psum, pssq, Wb,
                                       Qb, Kb, Vb, Sb, bar);
}